// Round 3
// baseline (12581.190 us; speedup 1.0000x reference)
//
#include <hip/hip_runtime.h>
#include <hip/hip_bf16.h>

// FARGAN vocoder. Sizes fixed by the reference:
#define SS      64
#define NSUB    4
#define LPREV   512
#define NF      193
#define NFRAMES 100
#define BATCH   64

// ---------- helpers ----------

__device__ __forceinline__ float bf2f(unsigned short u) {
    return __uint_as_float(((unsigned int)u) << 16);
}
__device__ __forceinline__ unsigned short f2bf(float x) {
    unsigned int u = __float_as_uint(x);
    return (unsigned short)((u + 0x7fffu + ((u >> 16) & 1u)) >> 16);
}
__device__ __forceinline__ float lo16(unsigned int u) { return __uint_as_float(u << 16); }
__device__ __forceinline__ float hi16(unsigned int u) { return __uint_as_float(u & 0xffff0000u); }

__device__ __forceinline__ float sigm(float x) {
    return 1.0f / (1.0f + expf(-x));
}

// load a bf16 pair (elements eoff, eoff+1; eoff even) regardless of src dtype
__device__ __forceinline__ unsigned int ldpair(int f32, const void* W, int eoff) {
    if (f32) {
        const float* p = (const float*)W + eoff;
        return ((unsigned int)f2bf(p[0])) | (((unsigned int)f2bf(p[1])) << 16);
    }
    return *(const unsigned int*)((const unsigned short*)W + eoff);
}
__device__ __forceinline__ float ld1f(int f32, const void* p, int i) {
    if (f32) return ((const float*)p)[i];
    return bf2f(((const unsigned short*)p)[i]);
}

// ---------- dtype detector ----------
// features[0,192,f] (period) in [64,300). Interpreted as fp32, 50/50 in-range
// hits => fp32 inputs; a bf16 buffer reinterpreted never passes.
__global__ void fargan_detect(const void* feats, int* flag) {
    const float* pf = (const float*)feats;
    int ok = 1;
    for (int f = 0; f < 50; ++f) {
        float v = pf[192 * NFRAMES + f];
        if (!(v >= 63.0f && v <= 301.0f)) { ok = 0; break; }
    }
    *flag = ok;   // 1 = fp32, 0 = bf16
}

// ---------- kernel 1: frame conv (parallel over B x FRAMES) ----------

template<bool F32>
__device__ __forceinline__ float dot_rt(const void* W, int off, const float* x, int nelem) {
    if constexpr (F32) {
        const float* w = (const float*)W + off;
        float a0 = 0.f, a1 = 0.f;
#pragma unroll 8
        for (int k = 0; k < nelem / 2; ++k) {
            a0 = fmaf(w[2 * k + 0], x[2 * k + 0], a0);
            a1 = fmaf(w[2 * k + 1], x[2 * k + 1], a1);
        }
        return a0 + a1;
    } else {
        const unsigned int* w2 = (const unsigned int*)((const unsigned short*)W + off);
        float a0 = 0.f, a1 = 0.f;
#pragma unroll 8
        for (int k = 0; k < nelem / 2; ++k) {
            unsigned int u = w2[k];
            a0 = fmaf(lo16(u), x[2 * k + 0], a0);
            a1 = fmaf(hi16(u), x[2 * k + 1], a1);
        }
        return a0 + a1;
    }
}

template<bool F32>
__device__ __forceinline__ void conv_body(
    const void* __restrict__ feats, const void* __restrict__ gfeat,
    const void* __restrict__ Wc1, const void* __restrict__ Wc2,
    const void* __restrict__ Wc3, float* __restrict__ cbuf)
{
    int blk = blockIdx.x;
    int b = blk / NFRAMES, f = blk - b * NFRAMES;
    int t = threadIdx.x;
    __shared__ float xa[256], xb[256];

    float v;
    if (t < 192) v = ld1f(F32 ? 1 : 0, feats, b * (NF * NFRAMES) + t * NFRAMES + f);
    else         v = ld1f(F32 ? 1 : 0, gfeat, b * 64 + (t - 192));
    xa[t] = v;
    __syncthreads();

    float acc = dot_rt<F32>(Wc1, t * 256, xa, 256);
    xb[t] = tanhf(acc);
    __syncthreads();

    acc = dot_rt<F32>(Wc2, t * 256, xb, 256);
    xa[t] = tanhf(acc);
    __syncthreads();

    float a0 = dot_rt<F32>(Wc3, t * 256, xa, 256);
    float a1 = dot_rt<F32>(Wc3, (t + 256) * 256, xa, 256);
    float* co = cbuf + (b * NFRAMES + f) * 512;
    co[t]       = tanhf(a0);
    co[t + 256] = tanhf(a1);
}

__global__ __launch_bounds__(256) void fargan_conv(
    const void* feats, const void* gfeat,
    const void* Wc1, const void* Wc2, const void* Wc3,
    const int* flag, float* cbuf)
{
    if (*flag) conv_body<true>(feats, gfeat, Wc1, Wc2, Wc3, cbuf);
    else       conv_body<false>(feats, gfeat, Wc1, Wc2, Wc3, cbuf);
}

// ---------- kernel 2: sequential recurrence ----------
// One WG (256 threads = 4 waves) per batch row. All weights preloaded once:
// registers (packed bf16 pairs, wave-uniform K-windows) + LDS (Wsd/Wsg/Wout,
// transposed [k2][row] so lane reads are conflict-free). The 400-step loop
// touches no global memory except crow (128 dwords/step) and the out store.

// GRU dot: pair-strided partition. Pair p = w + 4*i (i<72) of the per-row
// concat [r(96 pairs)|z(96)|in(64)|hn(32)]. Gate boundaries hit at i=24,48,64
// for EVERY wave -> compile-time accumulator routing, no switches.
// x element for pair p: xcat[(2p) mod 192], xcat = [in0(64)|ps(64)|s(64)].
__device__ __forceinline__ void gru_dot(const unsigned int* wr, const float* xc, int w,
                                        float& R, float& Z, float& I, float& H) {
    float r0=0,r1=0,z0=0,z1=0,i0=0,i1=0,h0=0,h1=0;
#pragma unroll
    for (int i = 0; i < 72; ++i) {
        int e0 = 2*w + 8*i - ((i >= 24) ? 192 : 0) - ((i >= 48) ? 192 : 0);
        float2 xv = *(const float2*)(xc + e0);
        unsigned int u = wr[i];
        float wl = lo16(u), wh = hi16(u);
        if (i < 24)      { r0 = fmaf(wl, xv.x, r0); r1 = fmaf(wh, xv.y, r1); }
        else if (i < 48) { z0 = fmaf(wl, xv.x, z0); z1 = fmaf(wh, xv.y, z1); }
        else if (i < 64) { i0 = fmaf(wl, xv.x, i0); i1 = fmaf(wh, xv.y, i1); }
        else             { h0 = fmaf(wl, xv.x, h0); h1 = fmaf(wh, xv.y, h1); }
    }
    R = r0 + r1; Z = z0 + z1; I = i0 + i1; H = h0 + h1;
}

// 25-chunk (100-elem, zero-padded) dot for Wfw: wave w covers elems [96w, ...)
__device__ __forceinline__ float dot_fw(const unsigned int* wr, const float4* cat4, int w) {
    float a0=0,a1=0,a2=0,a3=0;
#pragma unroll
    for (int i = 0; i < 25; ++i) {
        float4 xv = cat4[24*w + i];
        unsigned int u0 = wr[2*i], u1 = wr[2*i+1];
        a0 = fmaf(lo16(u0), xv.x, a0); a1 = fmaf(hi16(u0), xv.y, a1);
        a2 = fmaf(lo16(u1), xv.z, a2); a3 = fmaf(hi16(u1), xv.w, a3);
    }
    return (a0 + a1) + (a2 + a3);
}

// 16-elem wave-window dot (fwg / Wg glu): elems [16w, 16w+16) of a 64-vec
__device__ __forceinline__ float dot16(const unsigned int* wr, const float* x, int w) {
    float a0=0,a1=0,a2=0,a3=0;
#pragma unroll
    for (int i = 0; i < 4; ++i) {
        float4 xv = *(const float4*)(x + 16*w + 4*i);
        unsigned int u0 = wr[2*i], u1 = wr[2*i+1];
        a0 = fmaf(lo16(u0), xv.x, a0); a1 = fmaf(hi16(u0), xv.y, a1);
        a2 = fmaf(lo16(u1), xv.z, a2); a3 = fmaf(hi16(u1), xv.w, a3);
    }
    return (a0 + a1) + (a2 + a3);
}

__global__ __launch_bounds__(256, 1) void fargan_seq(
    const void* __restrict__ feats, const void* __restrict__ prev_in,
    const void* __restrict__ Wfw,  const void* __restrict__ Wfwg,
    const void* __restrict__ Wih1, const void* __restrict__ Whh1,
    const void* __restrict__ Wih2, const void* __restrict__ Whh2,
    const void* __restrict__ Wih3, const void* __restrict__ Whh3,
    const void* __restrict__ Wg1,  const void* __restrict__ Wg2,
    const void* __restrict__ Wg3,
    const void* __restrict__ Wsg,  const void* __restrict__ Wsd,
    const void* __restrict__ Wout,
    const int* __restrict__ flag, const float* __restrict__ cbuf,
    void* __restrict__ outp)
{
    const int t = threadIdx.x, b = blockIdx.x;
    const int w = t >> 6, j = t & 63;
    const int f32 = *flag;

    // ---- LDS ----
    __shared__ __align__(16) float hist[1024];     // prev-sample ring
    __shared__ __align__(16) float cat[388];       // fw input
    __shared__ __align__(16) float xcat[192];      // [in0|ps|s] per GRU
    __shared__ __align__(16) float skipx[320];     // [o1|o2|o3|fw|ps]
    __shared__ __align__(16) float sdb[128];
    __shared__ __align__(16) float sob[128];
    __shared__ __align__(16) float vpre[64];
    __shared__ __align__(16) float sfwb[128];
    __shared__ __align__(16) float sv[3][64];      // GRU states
    __shared__ float partA[4][64];                 // 1-acc phase partials
    __shared__ float part2[4][128];                // Wsd/Wsg partials
    __shared__ float part3[16][64];                // GRU partials [q*4+w][j]
    __shared__ unsigned int lw_sd[160 * 128];      // Wsd transposed pairs (80 KB)
    __shared__ unsigned int lw_sg[64 * 128];       // Wsg transposed (32 KB)
    __shared__ unsigned int lw_out[64 * 64];       // Wout transposed (16 KB)

    // ---- one-time register preload (all indices compile-time) ----
    unsigned int wfw[50];
#pragma unroll
    for (int i = 0; i < 50; ++i) wfw[i] = 0;
    {
        int npair = (w == 3) ? 50 : 48, e0 = 96 * w;
#pragma unroll
        for (int i = 0; i < 50; ++i)
            if (i < npair) wfw[i] = ldpair(f32, Wfw, j * 388 + e0 + 2 * i);
    }
    unsigned int wfwg[8];
#pragma unroll
    for (int i = 0; i < 8; ++i) wfwg[i] = ldpair(f32, Wfwg, j * 64 + 16 * w + 2 * i);

    const void* WihA[3] = {Wih1, Wih2, Wih3};
    const void* WhhA[3] = {Whh1, Whh2, Whh3};
    const void* WgA[3]  = {Wg1,  Wg2,  Wg3};

    unsigned int wgru[3][72];
#pragma unroll
    for (int G = 0; G < 3; ++G) {
#pragma unroll
        for (int i = 0; i < 72; ++i) {
            int c = 2 * (w + 4 * i);          // concat elem index [0,576)
            int g = c / 192, within = c - g * 192;
            wgru[G][i] = (within < 128)
                ? ldpair(f32, WihA[G], (g * 64 + j) * 128 + within)
                : ldpair(f32, WhhA[G], (g * 64 + j) * 64 + within - 128);
        }
    }
    unsigned int wg[3][8];
#pragma unroll
    for (int G = 0; G < 3; ++G)
#pragma unroll
        for (int i = 0; i < 8; ++i) wg[G][i] = ldpair(f32, WgA[G], j * 64 + 16 * w + 2 * i);

    // ---- one-time LDS weight preload (transposed pair layout) ----
    for (int i = t; i < 160 * 128; i += 256) { int k2 = i >> 7, jj = i & 127; lw_sd[i]  = ldpair(f32, Wsd,  jj * 320 + 2 * k2); }
    for (int i = t; i < 64 * 128;  i += 256) { int k2 = i >> 7, jj = i & 127; lw_sg[i]  = ldpair(f32, Wsg,  jj * 128 + 2 * k2); }
    for (int i = t; i < 64 * 64;   i += 256) { int k2 = i >> 6, jj = i & 63;  lw_out[i] = ldpair(f32, Wout, jj * 128 + 2 * k2); }

    for (int i = t; i < LPREV; i += 256) hist[i] = ld1f(f32, prev_in, b * LPREV + i);
    for (int i = t + LPREV; i < 1024; i += 256) hist[i] = 0.f;
    if (t < 64) { sv[0][t] = 0.f; sv[1][t] = 0.f; sv[2][t] = 0.f; }
    if (t < 128) sfwb[t] = 0.f;
    __syncthreads();

    const float4* cat4 = (const float4*)cat;
    const float4* skipx4 = (const float4*)skipx;
    const float4* sdb4 = (const float4*)sdb;
    const float4* sob4 = (const float4*)sob;

    int base = 0;
    for (int f = 0; f < NFRAMES; ++f) {
        int period = (int)rintf(ld1f(f32, feats, b * (NF * NFRAMES) + (NF - 1) * NFRAMES + f));
        const float* crow = cbuf + (b * NFRAMES + f) * 512;

        for (int k = 0; k < NSUB; ++k) {
            // ---- build cat / skipx(ps) / lookback; update sfw ----
            if (t < 64) {
                float pv = hist[(base + 448 + t) & 1023];
                cat[128 + t] = pv;
                skipx[256 + t] = pv;
            }
            if (t < 68) {
                int idx = LPREV - period + t - 2;
                if (idx >= LPREV) idx -= period;
                cat[192 + t] = hist[(base + idx) & 1023];
            }
            if (t < 128) {
                float c = crow[t * 4 + k];
                cat[t] = c;
                cat[260 + t] = sfwb[t];   // old sfw
                sfwb[t] = c;              // new sfw = feat2s
            }
            __syncthreads();

            // ---- fw pre ----
            partA[w][j] = dot_fw(wfw, cat4, w);
            __syncthreads();
            if (t < 64) vpre[t] = tanhf(partA[0][t] + partA[1][t] + partA[2][t] + partA[3][t]);
            __syncthreads();
            partA[w][j] = dot16(wfwg, vpre, w);
            __syncthreads();
            if (t < 64) skipx[192 + t] = vpre[t] * sigm(partA[0][t] + partA[1][t] + partA[2][t] + partA[3][t]);
            __syncthreads();

            // ---- 3 GRU + GLU stages ----
#pragma unroll
            for (int G = 0; G < 3; ++G) {
                if (t < 64)       xcat[t] = (G == 0) ? skipx[192 + t] : skipx[(G - 1) * 64 + t];
                else if (t < 128) xcat[t] = skipx[256 + (t - 64)];
                else if (t < 192) xcat[t] = sv[G][t - 128];
                __syncthreads();

                float R, Z, I, H;
                gru_dot(wgru[G], xcat, w, R, Z, I, H);
                part3[0 * 4 + w][j] = R;
                part3[1 * 4 + w][j] = Z;
                part3[2 * 4 + w][j] = I;
                part3[3 * 4 + w][j] = H;
                __syncthreads();

                if (t < 64) {
                    float r  = sigm(part3[0][t] + part3[1][t] + part3[2][t] + part3[3][t]);
                    float z  = sigm(part3[4][t] + part3[5][t] + part3[6][t] + part3[7][t]);
                    float in = part3[8][t] + part3[9][t] + part3[10][t] + part3[11][t];
                    float hn = part3[12][t] + part3[13][t] + part3[14][t] + part3[15][t];
                    float n = tanhf(in + r * hn);
                    sv[G][t] = (1.0f - z) * n + z * sv[G][t];
                }
                __syncthreads();

                partA[w][j] = dot16(wg[G], sv[G], w);
                __syncthreads();
                if (t < 64) skipx[G * 64 + t] = sv[G][t] * sigm(partA[0][t] + partA[1][t] + partA[2][t] + partA[3][t]);
                __syncthreads();
            }

            // ---- skip dense (LDS weights, transposed) ----
            {
                int kb = 40 * w;
#pragma unroll
                for (int pass = 0; pass < 2; ++pass) {
                    int jj = j + 64 * pass;
                    float a0=0,a1=0,a2=0,a3=0;
#pragma unroll
                    for (int xi = 0; xi < 20; ++xi) {
                        float4 xv = skipx4[20 * w + xi];
                        unsigned int u0 = lw_sd[(kb + 2 * xi) * 128 + jj];
                        unsigned int u1 = lw_sd[(kb + 2 * xi + 1) * 128 + jj];
                        a0 = fmaf(lo16(u0), xv.x, a0); a1 = fmaf(hi16(u0), xv.y, a1);
                        a2 = fmaf(lo16(u1), xv.z, a2); a3 = fmaf(hi16(u1), xv.w, a3);
                    }
                    part2[w][jj] = (a0 + a1) + (a2 + a3);
                }
            }
            __syncthreads();
            if (t < 128) sdb[t] = tanhf(part2[0][t] + part2[1][t] + part2[2][t] + part2[3][t]);
            __syncthreads();

            // ---- skip glu ----
            {
                int kb = 16 * w;
#pragma unroll
                for (int pass = 0; pass < 2; ++pass) {
                    int jj = j + 64 * pass;
                    float a0=0,a1=0,a2=0,a3=0;
#pragma unroll
                    for (int xi = 0; xi < 8; ++xi) {
                        float4 xv = sdb4[8 * w + xi];
                        unsigned int u0 = lw_sg[(kb + 2 * xi) * 128 + jj];
                        unsigned int u1 = lw_sg[(kb + 2 * xi + 1) * 128 + jj];
                        a0 = fmaf(lo16(u0), xv.x, a0); a1 = fmaf(hi16(u0), xv.y, a1);
                        a2 = fmaf(lo16(u1), xv.z, a2); a3 = fmaf(hi16(u1), xv.w, a3);
                    }
                    part2[w][jj] = (a0 + a1) + (a2 + a3);
                }
            }
            __syncthreads();
            if (t < 128) sob[t] = sdb[t] * sigm(part2[0][t] + part2[1][t] + part2[2][t] + part2[3][t]);
            __syncthreads();

            // ---- output layer ----
            {
                int kb = 16 * w;
                float a0=0,a1=0,a2=0,a3=0;
#pragma unroll
                for (int xi = 0; xi < 8; ++xi) {
                    float4 xv = sob4[8 * w + xi];
                    unsigned int u0 = lw_out[(kb + 2 * xi) * 64 + j];
                    unsigned int u1 = lw_out[(kb + 2 * xi + 1) * 64 + j];
                    a0 = fmaf(lo16(u0), xv.x, a0); a1 = fmaf(hi16(u0), xv.y, a1);
                    a2 = fmaf(lo16(u1), xv.z, a2); a3 = fmaf(hi16(u1), xv.w, a3);
                }
                partA[w][j] = (a0 + a1) + (a2 + a3);
            }
            __syncthreads();
            if (t < 64) {
                float ov = tanhf(partA[0][t] + partA[1][t] + partA[2][t] + partA[3][t]);
                hist[(base + 512 + t) & 1023] = ov;
                int oi = b * (NFRAMES * NSUB * SS) + f * (NSUB * SS) + k * SS + t;
                if (f32) ((float*)outp)[oi] = ov;
                else     ((unsigned short*)outp)[oi] = f2bf(ov);
            }
            __syncthreads();

            base += SS;
        }
    }
}

// ---------- launch ----------

extern "C" void kernel_launch(void* const* d_in, const int* in_sizes, int n_in,
                              void* d_out, int out_size, void* d_ws, size_t ws_size,
                              hipStream_t stream) {
    const void* feats = d_in[0];
    const void* gfeat = d_in[1];
    const void* prev  = d_in[2];
    const void* Wc1   = d_in[3];
    const void* Wc2   = d_in[4];
    const void* Wc3   = d_in[5];
    const void* Wfw   = d_in[6];
    const void* Wfwg  = d_in[7];
    const void* Wih1  = d_in[8];
    const void* Whh1  = d_in[9];
    const void* Wih2  = d_in[10];
    const void* Whh2  = d_in[11];
    const void* Wih3  = d_in[12];
    const void* Whh3  = d_in[13];
    const void* Wg1   = d_in[14];
    const void* Wg2   = d_in[15];
    const void* Wg3   = d_in[16];
    const void* Wsg   = d_in[17];
    const void* Wsd   = d_in[18];
    const void* Wout  = d_in[19];

    int*   flag = (int*)d_ws;                   // 1 int @ offset 0
    float* cbuf = (float*)((char*)d_ws + 256);  // 64*100*512 fp32 = 13.1 MB

    fargan_detect<<<1, 1, 0, stream>>>(feats, flag);
    fargan_conv<<<BATCH * NFRAMES, 256, 0, stream>>>(feats, gfeat, Wc1, Wc2, Wc3, flag, cbuf);
    fargan_seq<<<BATCH, 256, 0, stream>>>(feats, prev, Wfw, Wfwg,
                                          Wih1, Whh1, Wih2, Whh2, Wih3, Whh3,
                                          Wg1, Wg2, Wg3, Wsg, Wsd, Wout,
                                          flag, cbuf, d_out);
}

// Round 4
// 4158.628 us; speedup vs baseline: 3.0253x; 3.0253x over previous
//
#include <hip/hip_runtime.h>
#include <hip/hip_bf16.h>

// FARGAN vocoder on MI355X. Sizes fixed by the reference:
#define SS      64
#define NSUB    4
#define LPREV   512
#define NF      193
#define NFRAMES 100
#define BATCH   64
#define RPW     16     // batch rows per workgroup (MFMA M)

typedef __attribute__((ext_vector_type(8))) short   short8;   // 8 bf16 (4 VGPRs)
typedef __attribute__((ext_vector_type(4))) float   floatx4;  // MFMA C/D

// ---------- scalar helpers ----------
__device__ __forceinline__ float bf2f(unsigned short u) {
    return __uint_as_float(((unsigned int)u) << 16);
}
__device__ __forceinline__ unsigned short f2bf(float x) {
    unsigned int u = __float_as_uint(x);
    return (unsigned short)((u + 0x7fffu + ((u >> 16) & 1u)) >> 16);
}
__device__ __forceinline__ unsigned int packbf(float a, float b) {
    return (unsigned int)f2bf(a) | ((unsigned int)f2bf(b) << 16);
}
__device__ __forceinline__ float fsig(float x) { return 1.0f / (1.0f + __expf(-x)); }
__device__ __forceinline__ float ftanh(float x) {
    float e = __expf(-2.0f * fabsf(x));         // in (0,1], no overflow
    float t = 1.0f - 2.0f * e / (1.0f + e);
    return copysignf(t, x);
}
__device__ __forceinline__ float ld1f(int f32, const void* p, size_t i) {
    if (f32) return ((const float*)p)[i];
    return bf2f(((const unsigned short*)p)[i]);
}

// MFMA wrapper
__device__ __forceinline__ floatx4 mf(short8 a, short8 b, floatx4 c) {
    return __builtin_amdgcn_mfma_f32_16x16x32_bf16(a, b, c, 0, 0, 0);
}

// B-fragment preload: lane needs W[n][k0..k0+7] as 8 bf16 (zeros past realK).
__device__ __forceinline__ short8 ldfrag(int f32, const void* W, int Kdim, int realK,
                                         int n, int k0) {
    union { unsigned short h[8]; short8 s; } u;
#pragma unroll
    for (int i = 0; i < 8; ++i) {
        int k = k0 + i;
        unsigned short v = 0;
        if (k < realK)
            v = f32 ? f2bf(((const float*)W)[(size_t)n * Kdim + k])
                    : ((const unsigned short*)W)[(size_t)n * Kdim + k];
        u.h[i] = v;
    }
    return u.s;
}

// A-fragment from packed-bf16 LDS buffer: row m, k-block kb, quad q.
// strideU = row stride in uints (multiple of 4; 16B-aligned rows).
__device__ __forceinline__ short8 ldA(const unsigned short* buf, int strideU,
                                      int m, int kb, int q) {
    const unsigned int* p = (const unsigned int*)buf + m * strideU + kb * 16 + q * 4;
    uint4 u = *(const uint4*)p;
    return __builtin_bit_cast(short8, u);
}

// ---------- dtype detector ----------
// features[0,192,f] (period) in [64,300): 50/50 in-range as fp32 => fp32 inputs.
__global__ void fargan_detect(const void* feats, int* flag) {
    const float* pf = (const float*)feats;
    int ok = 1;
    for (int f = 0; f < 50; ++f) {
        float v = pf[192 * NFRAMES + f];
        if (!(v >= 63.0f && v <= 301.0f)) { ok = 0; break; }
    }
    *flag = ok;
}

// ---------- kernel 1: frame conv ----------
template<bool F32>
__device__ __forceinline__ float dot_rt(const void* W, int off, const float* x, int nelem) {
    if constexpr (F32) {
        const float* w = (const float*)W + off;
        float a0 = 0.f, a1 = 0.f;
#pragma unroll 8
        for (int k = 0; k < nelem / 2; ++k) {
            a0 = fmaf(w[2 * k + 0], x[2 * k + 0], a0);
            a1 = fmaf(w[2 * k + 1], x[2 * k + 1], a1);
        }
        return a0 + a1;
    } else {
        const unsigned int* w2 = (const unsigned int*)((const unsigned short*)W + off);
        float a0 = 0.f, a1 = 0.f;
#pragma unroll 8
        for (int k = 0; k < nelem / 2; ++k) {
            unsigned int u = w2[k];
            a0 = fmaf(__uint_as_float(u << 16),          x[2 * k + 0], a0);
            a1 = fmaf(__uint_as_float(u & 0xffff0000u), x[2 * k + 1], a1);
        }
        return a0 + a1;
    }
}

template<bool F32>
__device__ __forceinline__ void conv_body(
    const void* __restrict__ feats, const void* __restrict__ gfeat,
    const void* __restrict__ Wc1, const void* __restrict__ Wc2,
    const void* __restrict__ Wc3, float* __restrict__ cbuf)
{
    int blk = blockIdx.x;
    int b = blk / NFRAMES, f = blk - b * NFRAMES;
    int t = threadIdx.x;
    __shared__ float xa[256], xb[256];

    float v;
    if (t < 192) v = ld1f(F32 ? 1 : 0, feats, (size_t)b * (NF * NFRAMES) + t * NFRAMES + f);
    else         v = ld1f(F32 ? 1 : 0, gfeat, (size_t)b * 64 + (t - 192));
    xa[t] = v;
    __syncthreads();

    float acc = dot_rt<F32>(Wc1, t * 256, xa, 256);
    xb[t] = tanhf(acc);
    __syncthreads();

    acc = dot_rt<F32>(Wc2, t * 256, xb, 256);
    xa[t] = tanhf(acc);
    __syncthreads();

    float a0 = dot_rt<F32>(Wc3, t * 256, xa, 256);
    float a1 = dot_rt<F32>(Wc3, (t + 256) * 256, xa, 256);
    float* co = cbuf + ((size_t)b * NFRAMES + f) * 512;
    // transposed write: element e (= j*4+k) -> co[k*128 + j]
    int e0 = t, e1 = t + 256;
    co[(e0 & 3) * 128 + (e0 >> 2)] = tanhf(a0);
    co[(e1 & 3) * 128 + (e1 >> 2)] = tanhf(a1);
}

__global__ __launch_bounds__(256) void fargan_conv(
    const void* feats, const void* gfeat,
    const void* Wc1, const void* Wc2, const void* Wc3,
    const int* flag, float* cbuf)
{
    if (*flag) conv_body<true>(feats, gfeat, Wc1, Wc2, Wc3, cbuf);
    else       conv_body<false>(feats, gfeat, Wc1, Wc2, Wc3, cbuf);
}

// ---------- kernel 2: sequential recurrence (MFMA, resident weights) ----------
// 4 WGs x 16 batch rows. Wave w owns n-tiles [16w,16w+16) of every 64-wide
// layer (pairs {32w,32w+16} for the 128-wide ones). All N, full K per wave:
// no cross-wave reductions. B-frags resident in VGPR/AGPR; Wsd in LDS.

__global__ __launch_bounds__(256, 1) void fargan_seq(
    const void* __restrict__ feats, const void* __restrict__ prev_in,
    const void* __restrict__ Wfw,  const void* __restrict__ Wfwg,
    const void* __restrict__ Wih1, const void* __restrict__ Whh1,
    const void* __restrict__ Wih2, const void* __restrict__ Whh2,
    const void* __restrict__ Wih3, const void* __restrict__ Whh3,
    const void* __restrict__ Wg1,  const void* __restrict__ Wg2,
    const void* __restrict__ Wg3,
    const void* __restrict__ Wsg,  const void* __restrict__ Wsd,
    const void* __restrict__ Wout,
    const int* __restrict__ flag, const float* __restrict__ cbuf,
    void* __restrict__ outp)
{
    const int t = threadIdx.x;
    const int b0 = blockIdx.x * RPW;
    const int lane = t & 63, w = t >> 6;
    const int lq = lane >> 4, ln = lane & 15;
    const int nj = 16 * w + ln;            // n for 64-wide layers
    const int f32 = *flag;

    // ---- LDS (strides in uints: mult of 4, ≡4 mod 32 unless noted) ----
    __shared__ __align__(16) unsigned short hist[RPW * 520];   // bf16 ring, mod-512
    __shared__ __align__(16) unsigned short catb[RPW * 424];   // [feat2s|ps|look|sfw|0pad]
    __shared__ __align__(16) unsigned short xg  [RPW * 200];   // [in0|ps|s]
    __shared__ __align__(16) unsigned short skx [RPW * 328];   // [o1|o2|o3|fw|ps]
    __shared__ __align__(16) unsigned short sdbb[RPW * 136];
    __shared__ __align__(16) unsigned short sobb[RPW * 136];
    __shared__ __align__(16) unsigned short vpre[RPW * 72];
    __shared__ __align__(16) unsigned short svp [RPW * 72];    // packed s_new
    __shared__ float svf[3 * RPW * 68];                        // fp32 GRU states
    __shared__ __align__(16) unsigned short wsd[128 * 328];    // Wsd, 164u stride
    __shared__ int period_s[RPW];

    // ---- resident B-fragments (per lane) ----
    short8 Bfw[13], Bfwg[2], Bout[4];
    short8 Br[3][6], Bz[3][6], Bi[3][4], Bh[3][2], Bg[3][2];
    short8 Bsg[2][4];

    const void* WihA[3] = {Wih1, Wih2, Wih3};
    const void* WhhA[3] = {Whh1, Whh2, Whh3};
    const void* WgA[3]  = {Wg1,  Wg2,  Wg3};

#pragma unroll
    for (int kb = 0; kb < 13; ++kb) Bfw[kb] = ldfrag(f32, Wfw, 388, 388, nj, kb * 32 + lq * 8);
#pragma unroll
    for (int kb = 0; kb < 2; ++kb)  Bfwg[kb] = ldfrag(f32, Wfwg, 64, 64, nj, kb * 32 + lq * 8);
#pragma unroll
    for (int G = 0; G < 3; ++G) {
#pragma unroll
        for (int kb = 0; kb < 4; ++kb) {
            Br[G][kb] = ldfrag(f32, WihA[G], 128, 128, nj,       kb * 32 + lq * 8);
            Bz[G][kb] = ldfrag(f32, WihA[G], 128, 128, 64 + nj,  kb * 32 + lq * 8);
            Bi[G][kb] = ldfrag(f32, WihA[G], 128, 128, 128 + nj, kb * 32 + lq * 8);
        }
#pragma unroll
        for (int kb = 0; kb < 2; ++kb) {
            Br[G][4 + kb] = ldfrag(f32, WhhA[G], 64, 64, nj,       kb * 32 + lq * 8);
            Bz[G][4 + kb] = ldfrag(f32, WhhA[G], 64, 64, 64 + nj,  kb * 32 + lq * 8);
            Bh[G][kb]     = ldfrag(f32, WhhA[G], 64, 64, 128 + nj, kb * 32 + lq * 8);
            Bg[G][kb]     = ldfrag(f32, WgA[G],  64, 64, nj,       kb * 32 + lq * 8);
        }
    }
#pragma unroll
    for (int tile = 0; tile < 2; ++tile)
#pragma unroll
        for (int kb = 0; kb < 4; ++kb)
            Bsg[tile][kb] = ldfrag(f32, Wsg, 128, 128, 32 * w + tile * 16 + ln, kb * 32 + lq * 8);
#pragma unroll
    for (int kb = 0; kb < 4; ++kb) Bout[kb] = ldfrag(f32, Wout, 128, 128, nj, kb * 32 + lq * 8);

    // ---- Wsd -> LDS (164u stride rows; zeros past K=320) ----
    {
        int rr = t >> 1, half = t & 1;
        for (int c = half * 82; c < half * 82 + 82; ++c) {
            int k0 = 2 * c;
            unsigned int v = 0;
            if (k0 < 320) {
                if (f32) {
                    const float* p = (const float*)Wsd + (size_t)rr * 320 + k0;
                    v = packbf(p[0], p[1]);
                } else {
                    v = *(const unsigned int*)((const unsigned short*)Wsd + (size_t)rr * 320 + k0);
                }
            }
            ((unsigned int*)wsd)[rr * 164 + c] = v;
        }
    }

    // ---- zero init LDS state ----
    for (int i = t; i < RPW * 424; i += 256) catb[i] = 0;
    for (int i = t; i < RPW * 200; i += 256) xg[i] = 0;
    for (int i = t; i < RPW * 328; i += 256) skx[i] = 0;
    for (int i = t; i < RPW * 136; i += 256) { sdbb[i] = 0; sobb[i] = 0; }
    for (int i = t; i < RPW * 72;  i += 256) { vpre[i] = 0; svp[i] = 0; }
    for (int i = t; i < 3 * RPW * 68; i += 256) svf[i] = 0.f;
    for (int i = t; i < RPW * 512; i += 256) {
        int row = i >> 9, c = i & 511;
        hist[row * 520 + c] = f2bf(ld1f(f32, prev_in, (size_t)(b0 + row) * LPREV + c));
    }
    __syncthreads();

    int base = 0;
    for (int f = 0; f < NFRAMES; ++f) {
        if (t < RPW)
            period_s[t] = (int)rintf(ld1f(f32, feats,
                (size_t)(b0 + t) * (NF * NFRAMES) + (NF - 1) * NFRAMES + f));
        __syncthreads();

        for (int kk = 0; kk < NSUB; ++kk) {
            // ================= BUILD =================
            {
                int row = t >> 4, x16 = t & 15;
                unsigned int* cat32 = (unsigned int*)catb;
                int cb = row * 212;
                int e8 = x16 * 8;
                // old feat2s -> sfw slot [260:388)
                unsigned int o0 = cat32[cb + (e8 >> 1) + 0];
                unsigned int o1 = cat32[cb + (e8 >> 1) + 1];
                unsigned int o2 = cat32[cb + (e8 >> 1) + 2];
                unsigned int o3 = cat32[cb + (e8 >> 1) + 3];
                const float* cr = cbuf + ((size_t)(b0 + row) * NFRAMES + f) * 512 + kk * 128 + e8;
                float c0 = cr[0], c1 = cr[1], c2 = cr[2], c3 = cr[3];
                float c4 = cr[4], c5 = cr[5], c6 = cr[6], c7 = cr[7];
                cat32[cb + 130 + (e8 >> 1) + 0] = o0;
                cat32[cb + 130 + (e8 >> 1) + 1] = o1;
                cat32[cb + 130 + (e8 >> 1) + 2] = o2;
                cat32[cb + 130 + (e8 >> 1) + 3] = o3;
                cat32[cb + (e8 >> 1) + 0] = packbf(c0, c1);
                cat32[cb + (e8 >> 1) + 1] = packbf(c2, c3);
                cat32[cb + (e8 >> 1) + 2] = packbf(c4, c5);
                cat32[cb + (e8 >> 1) + 3] = packbf(c6, c7);
                // prev_sub -> cat[128:192), skx[256:320), xg[64:128)
                int i4 = x16 * 4;
#pragma unroll
                for (int ii = 0; ii < 4; ++ii) {
                    int i = i4 + ii;
                    unsigned short h = hist[row * 520 + ((base + 448 + i) & 511)];
                    catb[row * 424 + 128 + i] = h;
                    skx [row * 328 + 256 + i] = h;
                    xg  [row * 200 + 64  + i] = h;
                }
                // lookback -> cat[192:260)
                int per = period_s[row];
#pragma unroll
                for (int ii = 0; ii < 5; ++ii) {
                    int i = x16 * 5 + ii;
                    if (i < 68) {
                        int idx = 512 - per + i - 2;
                        if (idx >= 512) idx -= per;
                        catb[row * 424 + 192 + i] = hist[row * 520 + ((base + idx) & 511)];
                    }
                }
                // sv[0] -> xg s-slot
#pragma unroll
                for (int ii = 0; ii < 4; ++ii) {
                    int i = i4 + ii;
                    xg[row * 200 + 128 + i] = f2bf(svf[row * 68 + i]);
                }
            }
            __syncthreads();

            // ================= FW (tanh) =================
            {
                floatx4 C = {0.f, 0.f, 0.f, 0.f};
#pragma unroll
                for (int kb = 0; kb < 13; ++kb)
                    C = mf(ldA(catb, 212, ln, kb, lq), Bfw[kb], C);
#pragma unroll
                for (int r = 0; r < 4; ++r) {
                    int m = 4 * lq + r;
                    vpre[m * 72 + nj] = f2bf(ftanh(C[r]));
                }
            }
            __syncthreads();

            // ================= FWG (glu) =================
            {
                floatx4 C = {0.f, 0.f, 0.f, 0.f};
#pragma unroll
                for (int kb = 0; kb < 2; ++kb)
                    C = mf(ldA(vpre, 36, ln, kb, lq), Bfwg[kb], C);
#pragma unroll
                for (int r = 0; r < 4; ++r) {
                    int m = 4 * lq + r;
                    float vp = bf2f(vpre[m * 72 + nj]);
                    unsigned short ob = f2bf(vp * fsig(C[r]));
                    skx[m * 328 + 192 + nj] = ob;   // fw slot
                    xg [m * 200 + nj]       = ob;   // in0 for GRU1
                }
            }
            __syncthreads();

            // ================= GRU + GLU x3 =================
#pragma unroll
            for (int G = 0; G < 3; ++G) {
                // GRU dot + in-lane nonlinearity
                {
                    floatx4 Cr = {0.f,0.f,0.f,0.f}, Cz = {0.f,0.f,0.f,0.f};
                    floatx4 Ci = {0.f,0.f,0.f,0.f}, Ch = {0.f,0.f,0.f,0.f};
#pragma unroll
                    for (int kb = 0; kb < 6; ++kb) {
                        short8 a = ldA(xg, 100, ln, kb, lq);
                        Cr = mf(a, Br[G][kb], Cr);
                        Cz = mf(a, Bz[G][kb], Cz);
                        if (kb < 4) Ci = mf(a, Bi[G][kb], Ci);
                        else        Ch = mf(a, Bh[G][kb - 4], Ch);
                    }
#pragma unroll
                    for (int r = 0; r < 4; ++r) {
                        int m = 4 * lq + r;
                        float rr = fsig(Cr[r]);
                        float zz = fsig(Cz[r]);
                        float sold = svf[G * (RPW * 68) + m * 68 + nj];
                        float nn = ftanh(Ci[r] + rr * Ch[r]);
                        float sn = (1.0f - zz) * nn + zz * sold;
                        svf[G * (RPW * 68) + m * 68 + nj] = sn;
                        svp[m * 72 + nj] = f2bf(sn);
                    }
                }
                __syncthreads();
                // GLU on s_new; also stage sv[G+1] into xg s-slot
                {
                    floatx4 C = {0.f, 0.f, 0.f, 0.f};
#pragma unroll
                    for (int kb = 0; kb < 2; ++kb)
                        C = mf(ldA(svp, 36, ln, kb, lq), Bg[G][kb], C);
#pragma unroll
                    for (int r = 0; r < 4; ++r) {
                        int m = 4 * lq + r;
                        float sn = bf2f(svp[m * 72 + nj]);
                        unsigned short ob = f2bf(sn * fsig(C[r]));
                        skx[m * 328 + G * 64 + nj] = ob;
                        if (G < 2) xg[m * 200 + nj] = ob;     // in0 for next GRU
                    }
                    if (G < 2) {
                        int row = t >> 4, e4 = (t & 15) * 4;
#pragma unroll
                        for (int ii = 0; ii < 4; ++ii)
                            xg[row * 200 + 128 + e4 + ii] =
                                f2bf(svf[(G + 1) * (RPW * 68) + row * 68 + e4 + ii]);
                    }
                }
                __syncthreads();
            }

            // ================= SD (tanh), B from LDS =================
            {
                floatx4 C0 = {0.f,0.f,0.f,0.f}, C1 = {0.f,0.f,0.f,0.f};
                int n0 = 32 * w + ln, n1 = n0 + 16;
#pragma unroll
                for (int kb = 0; kb < 10; ++kb) {
                    short8 a  = ldA(skx, 164, ln, kb, lq);
                    short8 b0f = ldA(wsd, 164, n0, kb, lq);
                    short8 b1f = ldA(wsd, 164, n1, kb, lq);
                    C0 = mf(a, b0f, C0);
                    C1 = mf(a, b1f, C1);
                }
#pragma unroll
                for (int r = 0; r < 4; ++r) {
                    int m = 4 * lq + r;
                    sdbb[m * 136 + n0] = f2bf(ftanh(C0[r]));
                    sdbb[m * 136 + n1] = f2bf(ftanh(C1[r]));
                }
            }
            __syncthreads();

            // ================= SG (glu) =================
            {
                floatx4 C0 = {0.f,0.f,0.f,0.f}, C1 = {0.f,0.f,0.f,0.f};
                int n0 = 32 * w + ln, n1 = n0 + 16;
#pragma unroll
                for (int kb = 0; kb < 4; ++kb) {
                    short8 a = ldA(sdbb, 68, ln, kb, lq);
                    C0 = mf(a, Bsg[0][kb], C0);
                    C1 = mf(a, Bsg[1][kb], C1);
                }
#pragma unroll
                for (int r = 0; r < 4; ++r) {
                    int m = 4 * lq + r;
                    float s0 = bf2f(sdbb[m * 136 + n0]);
                    float s1 = bf2f(sdbb[m * 136 + n1]);
                    sobb[m * 136 + n0] = f2bf(s0 * fsig(C0[r]));
                    sobb[m * 136 + n1] = f2bf(s1 * fsig(C1[r]));
                }
            }
            __syncthreads();

            // ================= OUT (tanh) =================
            {
                floatx4 C = {0.f, 0.f, 0.f, 0.f};
#pragma unroll
                for (int kb = 0; kb < 4; ++kb)
                    C = mf(ldA(sobb, 68, ln, kb, lq), Bout[kb], C);
#pragma unroll
                for (int r = 0; r < 4; ++r) {
                    int m = 4 * lq + r;
                    float ov = ftanh(C[r]);
                    hist[m * 520 + ((base + nj) & 511)] = f2bf(ov);
                    size_t oi = (size_t)(b0 + m) * (NFRAMES * NSUB * SS)
                              + f * (NSUB * SS) + kk * SS + nj;
                    if (f32) ((float*)outp)[oi] = ov;
                    else     ((unsigned short*)outp)[oi] = f2bf(ov);
                }
            }
            __syncthreads();

            base += SS;
        }
    }
}

// ---------- launch ----------
extern "C" void kernel_launch(void* const* d_in, const int* in_sizes, int n_in,
                              void* d_out, int out_size, void* d_ws, size_t ws_size,
                              hipStream_t stream) {
    const void* feats = d_in[0];
    const void* gfeat = d_in[1];
    const void* prev  = d_in[2];
    const void* Wc1   = d_in[3];
    const void* Wc2   = d_in[4];
    const void* Wc3   = d_in[5];
    const void* Wfw   = d_in[6];
    const void* Wfwg  = d_in[7];
    const void* Wih1  = d_in[8];
    const void* Whh1  = d_in[9];
    const void* Wih2  = d_in[10];
    const void* Whh2  = d_in[11];
    const void* Wih3  = d_in[12];
    const void* Whh3  = d_in[13];
    const void* Wg1   = d_in[14];
    const void* Wg2   = d_in[15];
    const void* Wg3   = d_in[16];
    const void* Wsg   = d_in[17];
    const void* Wsd   = d_in[18];
    const void* Wout  = d_in[19];

    int*   flag = (int*)d_ws;                   // 1 int @ offset 0
    float* cbuf = (float*)((char*)d_ws + 256);  // 64*100*512 fp32 = 13.1 MB

    fargan_detect<<<1, 1, 0, stream>>>(feats, flag);
    fargan_conv<<<BATCH * NFRAMES, 256, 0, stream>>>(feats, gfeat, Wc1, Wc2, Wc3, flag, cbuf);
    fargan_seq<<<BATCH / RPW, 256, 0, stream>>>(feats, prev, Wfw, Wfwg,
                                                Wih1, Whh1, Wih2, Whh2, Wih3, Whh3,
                                                Wg1, Wg2, Wg3, Wsg, Wsd, Wout,
                                                flag, cbuf, d_out);
}